// Round 2
// baseline (621.534 us; speedup 1.0000x reference)
//
#include <hip/hip_runtime.h>
#include <stdint.h>

#define TOK  4096
#define KIN  4096
#define NOUT 12288

#define BM 128
#define BN 128
#define BK 64

typedef __attribute__((ext_vector_type(4))) int int32x4;

// ---------------------------------------------------------------------------
// Kernel 0: repack widened int32 weights -> packed int8.
// Harness contract: integer inputs arrive as const int* (int32), so the
// [OUT, IN] int8 weight is a 201 MB int32 buffer. One coalesced pass:
// each thread reads int4 (4 x int32) and writes one packed int (4 x int8).
// ---------------------------------------------------------------------------
__global__ __launch_bounds__(256) void repack_w(const int* __restrict__ w32,
                                                int8_t* __restrict__ w8)
{
    const size_t i = (size_t)blockIdx.x * 256 + threadIdx.x;   // int4 index
    const int4 v = ((const int4*)w32)[i];
    unsigned pack = ((unsigned)(uint8_t)(int8_t)v.x)
                  | ((unsigned)(uint8_t)(int8_t)v.y << 8)
                  | ((unsigned)(uint8_t)(int8_t)v.z << 16)
                  | ((unsigned)(uint8_t)(int8_t)v.w << 24);
    ((int*)w8)[i] = (int)pack;
}

// ---------------------------------------------------------------------------
// Kernel 1: per-token dynamic quantization.
// One 256-thread block per row. float4 loads, wave shuffle + LDS amax
// reduction, RTE round (rintf == jnp.round), clip, pack 4 x int8.
// ---------------------------------------------------------------------------
__global__ __launch_bounds__(256) void quant_rows(const float* __restrict__ x,
                                                  int8_t* __restrict__ xq,
                                                  float* __restrict__ ascale)
{
    const int row = blockIdx.x;
    const int tid = threadIdx.x;
    const float4* xr = (const float4*)(x + (size_t)row * KIN);

    float4 v[4];
    float m = 0.0f;
#pragma unroll
    for (int i = 0; i < 4; ++i) {
        v[i] = xr[tid + 256 * i];
        m = fmaxf(m, fmaxf(fmaxf(fabsf(v[i].x), fabsf(v[i].y)),
                           fmaxf(fabsf(v[i].z), fabsf(v[i].w))));
    }
#pragma unroll
    for (int off = 32; off > 0; off >>= 1)
        m = fmaxf(m, __shfl_down(m, off, 64));
    __shared__ float wm[4];
    if ((tid & 63) == 0) wm[tid >> 6] = m;
    __syncthreads();
    const float amax = fmaxf(fmaxf(wm[0], wm[1]), fmaxf(wm[2], wm[3]));
    const float s = fmaxf(amax / 127.0f, 1e-8f);
    if (tid == 0) ascale[row] = s;

    int* out32 = (int*)(xq + (size_t)row * KIN);
#pragma unroll
    for (int i = 0; i < 4; ++i) {
        float c[4] = {v[i].x, v[i].y, v[i].z, v[i].w};
        unsigned pack = 0;
#pragma unroll
        for (int j = 0; j < 4; ++j) {
            float r = rintf(c[j] / s);            // RTE == jnp.round
            r = fminf(fmaxf(r, -128.0f), 127.0f);
            pack |= ((unsigned)(uint8_t)(int8_t)(int)r) << (8 * j);
        }
        out32[tid + 256 * i] = (int)pack;
    }
}

// ---------------------------------------------------------------------------
// Kernel 2: int8 GEMM, m97 structure. C[M,N] = Aq[M,K] . W[N,K]^T, then
// dequant epilogue. 128x128 tile, BK=64, 4 waves (2x2), 4x4 MFMA tiles/wave.
// LDS staged via global_load_lds width=16 (lane-order contiguous, no pad).
// ---------------------------------------------------------------------------
#define GLOAD_LDS16(g, l)                                                     \
    __builtin_amdgcn_global_load_lds(                                         \
        (const __attribute__((address_space(1))) unsigned int*)(g),           \
        (__attribute__((address_space(3))) unsigned int*)(l), 16, 0, 0)

__global__ __launch_bounds__(256) void gemm_i8(const int8_t* __restrict__ A,
                                               const int8_t* __restrict__ B,
                                               const float* __restrict__ ascale,
                                               const float* __restrict__ wscale,
                                               const float* __restrict__ bias,
                                               float* __restrict__ C)
{
    __shared__ __align__(16) int8_t As[BM * BK];  // 8 KiB
    __shared__ __align__(16) int8_t Bs[BN * BK];  // 8 KiB

    const int tid  = threadIdx.x;
    const int lane = tid & 63;
    const int wave = tid >> 6;
    const int quad = lane >> 4;
    const int l16  = lane & 15;
    const int wm   = (wave >> 1) * 64;   // wave row offset within 128-tile
    const int wn   = (wave & 1) * 64;    // wave col offset
    const int m0   = blockIdx.y * BM;
    const int n0   = blockIdx.x * BN;

    int32x4 acc[4][4];
#pragma unroll
    for (int i = 0; i < 4; ++i)
#pragma unroll
        for (int j = 0; j < 4; ++j) acc[i][j] = (int32x4){0, 0, 0, 0};

    // Staging chunks: 512 x 16B per tile; thread t owns chunks t and t+256.
    // chunk c -> tile row c>>2, byte col (c&3)*16; LDS offset c*16
    // (lane-order contiguous: c = wave*64 + lane => base + lane*16).
    const int c0 = tid, c1 = tid + 256;
    const int8_t* gA0 = A + (size_t)(m0 + (c0 >> 2)) * KIN + (c0 & 3) * 16;
    const int8_t* gA1 = A + (size_t)(m0 + (c1 >> 2)) * KIN + (c1 & 3) * 16;
    const int8_t* gB0 = B + (size_t)(n0 + (c0 >> 2)) * KIN + (c0 & 3) * 16;
    const int8_t* gB1 = B + (size_t)(n0 + (c1 >> 2)) * KIN + (c1 & 3) * 16;
    int8_t* lA0 = As + c0 * 16;
    int8_t* lA1 = As + c1 * 16;
    int8_t* lB0 = Bs + c0 * 16;
    int8_t* lB1 = Bs + c1 * 16;

    for (int kk = 0; kk < KIN; kk += BK) {
        __syncthreads();                 // previous tile's LDS reads done
        GLOAD_LDS16(gA0 + kk, lA0);
        GLOAD_LDS16(gA1 + kk, lA1);
        GLOAD_LDS16(gB0 + kk, lB0);
        GLOAD_LDS16(gB1 + kk, lB1);
        __syncthreads();                 // staged data visible (vmcnt drained)

        int32x4 aF[4], bF[4];
#pragma unroll
        for (int t = 0; t < 4; ++t)
            aF[t] = *(const int32x4*)(As + (wm + t * 16 + l16) * BK + quad * 16);
#pragma unroll
        for (int t = 0; t < 4; ++t)
            bF[t] = *(const int32x4*)(Bs + (wn + t * 16 + l16) * BK + quad * 16);

#pragma unroll
        for (int i = 0; i < 4; ++i)
#pragma unroll
            for (int j = 0; j < 4; ++j)
                acc[i][j] = __builtin_amdgcn_mfma_i32_16x16x64_i8(
                    aF[i], bF[j], acc[i][j], 0, 0, 0);
    }

    // Epilogue: C/D layout col=lane&15, row=quad*4+reg (dtype-independent)
#pragma unroll
    for (int i = 0; i < 4; ++i) {
        const int mb = m0 + wm + i * 16 + quad * 4;
        const float as0 = ascale[mb + 0];
        const float as1 = ascale[mb + 1];
        const float as2 = ascale[mb + 2];
        const float as3 = ascale[mb + 3];
#pragma unroll
        for (int j = 0; j < 4; ++j) {
            const int n   = n0 + wn + j * 16 + l16;
            const float wsn = wscale[n];
            const float bn  = bias[n];
            float* Cp = C + (size_t)mb * NOUT + n;
            Cp[0 * (size_t)NOUT] = (float)acc[i][j][0] * as0 * wsn + bn;
            Cp[1 * (size_t)NOUT] = (float)acc[i][j][1] * as1 * wsn + bn;
            Cp[2 * (size_t)NOUT] = (float)acc[i][j][2] * as2 * wsn + bn;
            Cp[3 * (size_t)NOUT] = (float)acc[i][j][3] * as3 * wsn + bn;
        }
    }
}

extern "C" void kernel_launch(void* const* d_in, const int* in_sizes, int n_in,
                              void* d_out, int out_size, void* d_ws, size_t ws_size,
                              hipStream_t stream)
{
    (void)in_sizes; (void)n_in; (void)out_size; (void)ws_size;
    const float* x      = (const float*)d_in[0];
    const int*   w32    = (const int*)d_in[1];      // int8 widened to int32
    const float* wscale = (const float*)d_in[2];
    const float* bias   = (const float*)d_in[3];
    float*       out    = (float*)d_out;

    int8_t* xq     = (int8_t*)d_ws;                               // 16 MiB
    float*  ascale = (float*)((char*)d_ws + (size_t)TOK * KIN);   // 16 KiB
    int8_t* w8     = (int8_t*)((char*)d_ws + (size_t)TOK * KIN + 65536);

    repack_w<<<(size_t)NOUT * KIN / 4 / 256, 256, 0, stream>>>(w32, w8);
    quant_rows<<<TOK, 256, 0, stream>>>(x, xq, ascale);
    dim3 grid(NOUT / BN, TOK / BM);
    gemm_i8<<<grid, 256, 0, stream>>>(xq, w8, ascale, wscale, bias, out);
}

// Round 3
// 612.762 us; speedup vs baseline: 1.0143x; 1.0143x over previous
//
#include <hip/hip_runtime.h>
#include <stdint.h>

#define TOK  4096
#define KIN  4096
#define NOUT 12288

#define BM 128
#define BN 128
#define BK 64

typedef __attribute__((ext_vector_type(4))) int int32x4;

// ---------------------------------------------------------------------------
// Kernel 0: repack widened int32 weights -> packed int8.
// int8 inputs arrive widened to int32 (harness contract); one coalesced pass.
// ---------------------------------------------------------------------------
__global__ __launch_bounds__(256) void repack_w(const int* __restrict__ w32,
                                                int8_t* __restrict__ w8)
{
    const size_t i = (size_t)blockIdx.x * 256 + threadIdx.x;   // int4 index
    const int4 v = ((const int4*)w32)[i];
    unsigned pack = ((unsigned)(uint8_t)(int8_t)v.x)
                  | ((unsigned)(uint8_t)(int8_t)v.y << 8)
                  | ((unsigned)(uint8_t)(int8_t)v.z << 16)
                  | ((unsigned)(uint8_t)(int8_t)v.w << 24);
    ((int*)w8)[i] = (int)pack;
}

// ---------------------------------------------------------------------------
// Kernel 1: per-token dynamic quantization.
// One 256-thread block per row. float4 coalesced loads, wave shuffle + LDS
// amax reduction, ONE divide (reciprocal) then RTE round via rintf.
// ---------------------------------------------------------------------------
__global__ __launch_bounds__(256) void quant_rows(const float* __restrict__ x,
                                                  int8_t* __restrict__ xq,
                                                  float* __restrict__ ascale)
{
    const int row = blockIdx.x;
    const int tid = threadIdx.x;
    const float4* xr = (const float4*)(x + (size_t)row * KIN);

    float4 v[4];
    float m = 0.0f;
#pragma unroll
    for (int i = 0; i < 4; ++i) {
        v[i] = xr[tid + 256 * i];
        m = fmaxf(m, fmaxf(fmaxf(fabsf(v[i].x), fabsf(v[i].y)),
                           fmaxf(fabsf(v[i].z), fabsf(v[i].w))));
    }
#pragma unroll
    for (int off = 32; off > 0; off >>= 1)
        m = fmaxf(m, __shfl_down(m, off, 64));
    __shared__ float wm[4];
    if ((tid & 63) == 0) wm[tid >> 6] = m;
    __syncthreads();
    const float amax = fmaxf(fmaxf(wm[0], wm[1]), fmaxf(wm[2], wm[3]));
    const float s   = fmaxf(amax / 127.0f, 1e-8f);
    const float inv = 1.0f / s;                    // one divide per thread
    if (tid == 0) ascale[row] = s;

    int* out32 = (int*)(xq + (size_t)row * KIN);
#pragma unroll
    for (int i = 0; i < 4; ++i) {
        float c[4] = {v[i].x, v[i].y, v[i].z, v[i].w};
        unsigned pack = 0;
#pragma unroll
        for (int j = 0; j < 4; ++j) {
            float r = rintf(c[j] * inv);           // RTE == jnp.round
            r = fminf(fmaxf(r, -128.0f), 127.0f);
            pack |= ((unsigned)(uint8_t)(int8_t)(int)r) << (8 * j);
        }
        out32[tid + 256 * i] = (int)pack;
    }
}

// ---------------------------------------------------------------------------
// Kernel 2: int8 GEMM, m97 structure + XOR-swizzled LDS.
// C[M,N] = Aq[M,K] . W[N,K]^T, dequant epilogue. 128x128 tile, BK=64,
// 4 waves (2x2), 4x4 mfma_i32_16x16x64_i8 per wave.
//
// LDS swizzle: logical 16B chunk (row r, chunk c) lives at slot
//   p = r*4 + ((c + (r>>1)) & 3)            (addr = p*16)
// Staging writes stay lane-contiguous (global_load_lds rule: LDS dest =
// wave-uniform base + lane*16); only the per-lane GLOBAL pointer is permuted.
// Readers: within a 16-lane ds_read_b128 phase (uniform quad), granule =
// (4*row + (quad + (row>>1))&3) mod 8 covers all 8 bank-groups 2-way -> free.
// ---------------------------------------------------------------------------
#define GLOAD_LDS16(g, l)                                                     \
    __builtin_amdgcn_global_load_lds(                                         \
        (const __attribute__((address_space(1))) unsigned int*)(g),           \
        (__attribute__((address_space(3))) unsigned int*)(l), 16, 0, 0)

__global__ __launch_bounds__(256) void gemm_i8(const int8_t* __restrict__ A,
                                               const int8_t* __restrict__ B,
                                               const float* __restrict__ ascale,
                                               const float* __restrict__ wscale,
                                               const float* __restrict__ bias,
                                               float* __restrict__ C)
{
    __shared__ __align__(16) int8_t As[BM * BK];  // 8 KiB
    __shared__ __align__(16) int8_t Bs[BN * BK];  // 8 KiB

    const int tid  = threadIdx.x;
    const int lane = tid & 63;
    const int wave = tid >> 6;
    const int quad = lane >> 4;
    const int l16  = lane & 15;
    const int wm   = (wave >> 1) * 64;
    const int wn   = (wave & 1) * 64;
    const int m0   = blockIdx.y * BM;
    const int n0   = blockIdx.x * BN;

    int32x4 acc[4][4];
#pragma unroll
    for (int i = 0; i < 4; ++i)
#pragma unroll
        for (int j = 0; j < 4; ++j) acc[i][j] = (int32x4){0, 0, 0, 0};

    // Staging: 512 slots x 16B per tile; thread t fills slots t and t+256.
    // Slot p holds (r = p>>2, chunk c = ((p&3) - (r>>1)) & 3).
    const int p0 = tid, p1 = tid + 256;
    const int r0 = p0 >> 2, ch0 = ((p0 & 3) - (r0 >> 1)) & 3;
    const int r1 = p1 >> 2, ch1 = ((p1 & 3) - (r1 >> 1)) & 3;
    const int8_t* gA0 = A + (size_t)(m0 + r0) * KIN + ch0 * 16;
    const int8_t* gA1 = A + (size_t)(m0 + r1) * KIN + ch1 * 16;
    const int8_t* gB0 = B + (size_t)(n0 + r0) * KIN + ch0 * 16;
    const int8_t* gB1 = B + (size_t)(n0 + r1) * KIN + ch1 * 16;
    int8_t* lA0 = As + p0 * 16;
    int8_t* lA1 = As + p1 * 16;
    int8_t* lB0 = Bs + p0 * 16;
    int8_t* lB1 = Bs + p1 * 16;

    for (int kk = 0; kk < KIN; kk += BK) {
        __syncthreads();                 // previous tile's LDS reads done
        GLOAD_LDS16(gA0 + kk, lA0);
        GLOAD_LDS16(gA1 + kk, lA1);
        GLOAD_LDS16(gB0 + kk, lB0);
        GLOAD_LDS16(gB1 + kk, lB1);
        __syncthreads();                 // staged data visible

        int32x4 aF[4], bF[4];
#pragma unroll
        for (int t = 0; t < 4; ++t) {
            const int rA = wm + t * 16 + l16;
            aF[t] = *(const int32x4*)(As + rA * 64 +
                                      ((quad + (rA >> 1)) & 3) * 16);
        }
#pragma unroll
        for (int t = 0; t < 4; ++t) {
            const int rB = wn + t * 16 + l16;
            bF[t] = *(const int32x4*)(Bs + rB * 64 +
                                      ((quad + (rB >> 1)) & 3) * 16);
        }

#pragma unroll
        for (int i = 0; i < 4; ++i)
#pragma unroll
            for (int j = 0; j < 4; ++j)
                acc[i][j] = __builtin_amdgcn_mfma_i32_16x16x64_i8(
                    aF[i], bF[j], acc[i][j], 0, 0, 0);
    }

    // Epilogue: C/D layout col=lane&15, row=quad*4+reg (dtype-independent)
#pragma unroll
    for (int i = 0; i < 4; ++i) {
        const int mb = m0 + wm + i * 16 + quad * 4;
        const float as0 = ascale[mb + 0];
        const float as1 = ascale[mb + 1];
        const float as2 = ascale[mb + 2];
        const float as3 = ascale[mb + 3];
#pragma unroll
        for (int j = 0; j < 4; ++j) {
            const int n   = n0 + wn + j * 16 + l16;
            const float wsn = wscale[n];
            const float bn  = bias[n];
            float* Cp = C + (size_t)mb * NOUT + n;
            Cp[0 * (size_t)NOUT] = (float)acc[i][j][0] * as0 * wsn + bn;
            Cp[1 * (size_t)NOUT] = (float)acc[i][j][1] * as1 * wsn + bn;
            Cp[2 * (size_t)NOUT] = (float)acc[i][j][2] * as2 * wsn + bn;
            Cp[3 * (size_t)NOUT] = (float)acc[i][j][3] * as3 * wsn + bn;
        }
    }
}

extern "C" void kernel_launch(void* const* d_in, const int* in_sizes, int n_in,
                              void* d_out, int out_size, void* d_ws, size_t ws_size,
                              hipStream_t stream)
{
    (void)in_sizes; (void)n_in; (void)out_size; (void)ws_size;
    const float* x      = (const float*)d_in[0];
    const int*   w32    = (const int*)d_in[1];      // int8 widened to int32
    const float* wscale = (const float*)d_in[2];
    const float* bias   = (const float*)d_in[3];
    float*       out    = (float*)d_out;

    int8_t* xq     = (int8_t*)d_ws;                               // 16 MiB
    float*  ascale = (float*)((char*)d_ws + (size_t)TOK * KIN);   // 16 KiB
    int8_t* w8     = (int8_t*)((char*)d_ws + (size_t)TOK * KIN + 65536);

    repack_w<<<(size_t)NOUT * KIN / 4 / 256, 256, 0, stream>>>(w32, w8);
    quant_rows<<<TOK, 256, 0, stream>>>(x, xq, ascale);
    dim3 grid(NOUT / BN, TOK / BM);
    gemm_i8<<<grid, 256, 0, stream>>>(xq, w8, ascale, wscale, bias, out);
}